// Round 11
// baseline (387.417 us; speedup 1.0000x reference)
//
#include <hip/hip_runtime.h>
#include <math.h>

#define N 3072
#define FEAT 128
#define NE 24576
#define PSTRIDE 64         // per-node pair-slot row stride
#define DOTB 768           // k_init dot blocks (4 nodes each)
#define GATB 192           // gather blocks in k_pgr2
#define AZ4 2360064        // f4 count of [Anew|new_batch]
#define AZB 577            // Anew zero blocks (4096 f4 each, bounds-checked)
#define RESCAP 4096        // residual-edge LDS capacity

// Wave-aggregated atomic add: one atomicAdd per distinct key per wave.
// All 64 lanes must reach this call (use `valid`, not early-return).
__device__ __forceinline__ void wave_agg_add(bool valid, int key, float val,
                                             float* base, int stride, int off) {
    int lane = threadIdx.x & 63;
    unsigned long long active = __ballot(valid ? 1 : 0);
    while (active) {
        int leader = __ffsll(active) - 1;
        int lkey = __shfl(key, leader);
        bool mine = valid && (key == lkey);
        unsigned long long grp = __ballot(mine ? 1 : 0);
        float v = mine ? val : 0.0f;
        #pragma unroll
        for (int o = 32; o; o >>= 1) v += __shfl_xor(v, o);
        if (lane == leader)
            atomicAdd(&base[(size_t)lkey * stride + off], v);
        active &= ~grp;
    }
}

__device__ __forceinline__ int ctrl_ld(const int* p) {
    return __hip_atomic_load(p, __ATOMIC_RELAXED, __HIP_MEMORY_SCOPE_AGENT);
}

// blocks [0,DOTB): a[i]=x[i].w[0:128], c[i]=x[i].w[128:256] (wave per node)
// block DOTB: zero [ctrl|pcnt|notsing] (1540 f4 = 24,640 B)
__global__ void k_init(const float* __restrict__ x, const float* __restrict__ w,
                       float* __restrict__ a, float* __restrict__ c,
                       float4* __restrict__ zws) {
    int b = blockIdx.x, t = threadIdx.x;
    if (b < DOTB) {
        int node = b * 4 + (t >> 6);
        int lane = t & 63;
        const float* xi = x + node * FEAT;
        float pa = xi[lane] * w[lane] + xi[lane + 64] * w[lane + 64];
        float pc = xi[lane] * w[FEAT + lane] + xi[lane + 64] * w[FEAT + lane + 64];
        for (int off = 32; off; off >>= 1) {
            pa += __shfl_down(pa, off);
            pc += __shfl_down(pc, off);
        }
        if (lane == 0) { a[node] = pa; c[node] = pc; }
    } else {
        float4 z = {0.f, 0.f, 0.f, 0.f};
        #pragma unroll
        for (int k = 0; k < 7; ++k) {
            int idx = k * 256 + t;
            if (idx < 1540) zws[idx] = z;
        }
    }
}

// score both directions, pack ep (u|v<<12|fu<<24|fv<<25), mark not-single,
// append (e,p) to q's gather row (dup pairs deduped at gather).
__global__ void k_edge_pairs(const int* __restrict__ ei, const float* __restrict__ a,
                             const float* __restrict__ c, const float* __restrict__ bb,
                             unsigned* __restrict__ ep, int* __restrict__ notsingle,
                             int* __restrict__ pcnt, unsigned long long* __restrict__ ptab) {
    int t = blockIdx.x * blockDim.x + threadIdx.x;
    if (t >= NE) return;
    int u = ei[t], v = ei[NE + t];
    unsigned wpk = (unsigned)u | ((unsigned)v << 12);
    if (u != v) {
        float b = bb[0];
        float su = a[u] + c[v] + b;    // S[u,v]; A_c[u,v]  (edge u->v)
        float sv = a[v] + c[u] + b;    // S[v,u]; A_c[v,u]  (edge v->u)
        unsigned fu = (su > 0.f) ? 1u : 0u;
        unsigned fv = (sv > 0.f) ? 1u : 0u;
        wpk |= (fu << 24) | (fv << 25);
        if (fu | fv) { notsingle[u] = 1; notsingle[v] = 1; }
        float eu = tanhf(su);
        int sl = atomicAdd(&pcnt[v], 1);
        if (sl < PSTRIDE)
            ptab[(size_t)v * PSTRIDE + sl] =
                ((unsigned long long)__float_as_uint(eu) << 32) | (unsigned)u;
        float ev2 = tanhf(sv);
        sl = atomicAdd(&pcnt[u], 1);
        if (sl < PSTRIDE)
            ptab[(size_t)u * PSTRIDE + sl] =
                ((unsigned long long)__float_as_uint(ev2) << 32) | (unsigned)v;
    }
    ep[t] = wpk;
}

// block 0: reach-to-0 bitmap + residual fixpoint + rank + cluster; ctrl[2]=1.
// blocks 1..GATB: zero Xnew slice (ctrl[4]) -> register gather -> join spin
//   (ctrl[4]==GATB, ctrl[2]==1, ctrl[3]==AZB) -> block-agg X-add + A-count.
// blocks GATB+1..: zero [Anew|new_batch], signal ctrl[3], exit (never spin).
__global__ void __launch_bounds__(1024)
k_pgr2(const unsigned* __restrict__ ep, const float* __restrict__ x,
       const int* __restrict__ pcnt, const unsigned long long* __restrict__ ptab,
       const int* __restrict__ notsingle, int* __restrict__ cluster,
       float* __restrict__ out_cluster, float* __restrict__ Xnew,
       float* __restrict__ Anew, int* __restrict__ ctrl) {
    __shared__ int lab[N];
    __shared__ unsigned Vw[N / 32];          // reach-to-0 bitmap
    __shared__ unsigned res[RESCAP];         // residual directed edges (p | q<<12)
    __shared__ unsigned short rnodes[N];     // residual node list
    __shared__ int ssum[1024];
    __shared__ unsigned short rk[N];
    __shared__ int sh_p[16 * 64];
    __shared__ int sh_cq[16];
    __shared__ float sh_a0[16 * 64];
    __shared__ float sh_a1[16 * 64];
    __shared__ int flag, rescnt, rncnt;
    int t = threadIdx.x, blk = blockIdx.x;
    int wv = t >> 6, lane = t & 63;
    if (blk == 0) {
        if (t < N / 32) Vw[t] = (t == 0) ? 1u : 0u;
        if (t == 0) { rescnt = 0; rncnt = 0; }
        unsigned act = 0x00FFFFFFu;          // 24 edges per thread, strided
        // ---- V sweeps: u joins V if (u->v flagged) && v in V ----
        for (;;) {
            __syncthreads();
            if (t == 0) flag = 0;
            __syncthreads();
            unsigned rem = act;
            while (rem) {
                int j = __ffs(rem) - 1;
                rem &= rem - 1;
                unsigned wpk = ep[t + j * 1024];
                if (!(wpk & 0x3000000u)) { act &= ~(1u << j); continue; }
                int u = wpk & 0xFFF, v = (wpk >> 12) & 0xFFF;
                unsigned pu = (Vw[u >> 5] >> (u & 31)) & 1u;
                unsigned pv = (Vw[v >> 5] >> (v & 31)) & 1u;
                if ((wpk & (1u << 24)) && pv && !pu) {
                    atomicOr(&Vw[u >> 5], 1u << (u & 31)); pu = 1; flag = 1;
                }
                if ((wpk & (1u << 25)) && pu && !pv) {
                    atomicOr(&Vw[v >> 5], 1u << (v & 31)); pv = 1; flag = 1;
                }
                bool done = (pu || !(wpk & (1u << 24))) && (pv || !(wpk & (1u << 25)));
                if (done) act &= ~(1u << j);
            }
            __syncthreads();
            if (!flag) break;
        }
        // ---- compact residue (sources not in V); residue is closed ----
        unsigned rem = act;
        while (rem) {
            int j = __ffs(rem) - 1;
            rem &= rem - 1;
            unsigned wpk = ep[t + j * 1024];
            int u = wpk & 0xFFF, v = (wpk >> 12) & 0xFFF;
            unsigned pu = (Vw[u >> 5] >> (u & 31)) & 1u;
            unsigned pv = (Vw[v >> 5] >> (v & 31)) & 1u;
            if ((wpk & (1u << 24)) && !pu) {     // lab[u] <- lab[v]
                int pos = atomicAdd(&rescnt, 1);
                if (pos < RESCAP) res[pos] = (unsigned)u | ((unsigned)v << 12);
            }
            if ((wpk & (1u << 25)) && !pv) {     // lab[v] <- lab[u]
                int pos = atomicAdd(&rescnt, 1);
                if (pos < RESCAP) res[pos] = (unsigned)v | ((unsigned)u << 12);
            }
        }
        // labels: V nodes -> 0; others identity
        for (int i = t; i < N; i += 1024) {
            unsigned inV = (Vw[i >> 5] >> (i & 31)) & 1u;
            lab[i] = inV ? 0 : i;
            if (!inV) {
                int pos = atomicAdd(&rncnt, 1);
                rnodes[pos] = (unsigned short)i;
            }
        }
        __syncthreads();
        int nres = rescnt < RESCAP ? rescnt : RESCAP;
        bool ovf = (rescnt > RESCAP);
        int nrn = rncnt;
        // ---- residual fixpoint (tiny; fallback to full edges on overflow) ----
        for (;;) {
            __syncthreads();
            if (t == 0) flag = 0;
            __syncthreads();
            if (!ovf) {
                for (int k = t; k < nres; k += 1024) {
                    unsigned w2 = res[k];
                    int p = w2 & 0xFFF, q = (w2 >> 12) & 0xFFF;
                    int lq = lab[q];
                    if (lq < lab[p]) { atomicMin(&lab[p], lq); flag = 1; }
                }
                for (int k = t; k < nrn; k += 1024) {
                    int i = rnodes[k];
                    int m = lab[i];
                    int mm = lab[m];
                    while (mm < m) { m = mm; mm = lab[m]; }
                    if (m < lab[i]) { atomicMin(&lab[i], m); flag = 1; }
                }
            } else {
                for (int j = 0; j < 24; ++j) {
                    unsigned wpk = ep[t + j * 1024];
                    int u = wpk & 0xFFF, v = (wpk >> 12) & 0xFFF;
                    if (wpk & (1u << 24)) {
                        int lv = lab[v];
                        if (lv < lab[u]) { atomicMin(&lab[u], lv); flag = 1; }
                    }
                    if (wpk & (1u << 25)) {
                        int lu = lab[u];
                        if (lu < lab[v]) { atomicMin(&lab[v], lu); flag = 1; }
                    }
                }
                for (int i = t; i < N; i += 1024) {
                    int m = lab[i];
                    if (m == 0) continue;
                    int mm = lab[m];
                    while (mm < m) { m = mm; mm = lab[m]; }
                    if (m < lab[i]) { atomicMin(&lab[i], m); flag = 1; }
                }
            }
            __syncthreads();
            if (!flag) break;
        }
        // ---- rank roots: cumsum(lab[i]==i)-1; cluster[j]=rank[lab[j]] ----
        int i0 = 3 * t;
        int r0 = (lab[i0] == i0);
        int r1 = (lab[i0 + 1] == i0 + 1);
        int r2 = (lab[i0 + 2] == i0 + 2);
        int s = r0 + r1 + r2;
        ssum[t] = s;
        __syncthreads();
        for (int off = 1; off < 1024; off <<= 1) {
            int val = (t >= off) ? ssum[t - off] : 0;
            __syncthreads();
            ssum[t] += val;
            __syncthreads();
        }
        int run = ssum[t] - s;
        run += r0; rk[i0]     = (unsigned short)(run - 1);
        run += r1; rk[i0 + 1] = (unsigned short)(run - 1);
        run += r2; rk[i0 + 2] = (unsigned short)(run - 1);
        __syncthreads();
        for (int j = t; j < N; j += 1024) {
            int cl = rk[lab[j]];
            cluster[j] = cl;
            out_cluster[j] = (float)cl;
        }
        __syncthreads();
        __threadfence();
        if (t == 0) atomicAdd(&ctrl[2], 1);
    } else if (blk <= GATB) {
        // ---- zero my Xnew slice (512 f4), signal ----
        {
            float4 z = {0.f, 0.f, 0.f, 0.f};
            if (t < 512) ((float4*)Xnew)[(blk - 1) * 512 + t] = z;
            __syncthreads();
            __threadfence();
            if (t == 0) atomicAdd(&ctrl[4], 1);
        }
        // ---- register gather for q = (blk-1)*16 + wv ----
        int q = (blk - 1) * 16 + wv;
        int cnt = pcnt[q]; if (cnt > PSTRIDE) cnt = PSTRIDE;
        const unsigned long long* row = ptab + (size_t)q * PSTRIDE;
        int myp = -1 - lane;      // unique negative: never matches a real p
        float mye = 0.f;
        if (lane < cnt) {
            unsigned long long s = row[lane];
            myp = (int)(s & 0xFFFFFFFFu);
            mye = __uint_as_float((unsigned)(s >> 32));
        }
        sh_p[wv * 64 + lane] = myp;
        bool dup = false;
        for (int j = 0; j < lane && !dup; ++j)
            dup = (sh_p[wv * 64 + j] == myp);
        bool valid = (lane < cnt) && !dup;
        unsigned long long m = __ballot(valid ? 1 : 0);
        float acc0 = 0.f, acc1 = 0.f;
        for (int j = 0; j < cnt; ++j) {
            if (!((m >> j) & 1ull)) continue;
            int p = __shfl(myp, j);
            float e = __shfl(mye, j);
            const float* xp = x + p * FEAT;
            acc0 += e * xp[lane];
            acc1 += e * xp[lane + 64];
        }
        if (!notsingle[q]) {
            const float* xq = x + q * FEAT;
            acc0 += xq[lane];
            acc1 += xq[lane + 64];
        }
        // ---- join: all Xnew slices zeroed, cluster ready, Anew zeroed ----
        if (t == 0) {
            while (ctrl_ld(&ctrl[4]) < GATB) __builtin_amdgcn_s_sleep(2);
            while (ctrl_ld(&ctrl[2]) < 1)    __builtin_amdgcn_s_sleep(2);
            while (ctrl_ld(&ctrl[3]) < AZB)  __builtin_amdgcn_s_sleep(2);
        }
        __syncthreads();
        __threadfence();
        // ---- block-aggregated X-add ----
        int cq = cluster[q];
        if (lane == 0) sh_cq[wv] = cq;
        sh_a0[wv * 64 + lane] = acc0;
        sh_a1[wv * 64 + lane] = acc1;
        __syncthreads();
        bool leader = true;
        for (int j = 0; j < wv; ++j)
            if (sh_cq[j] == cq) leader = false;
        if (leader) {
            float s0 = acc0, s1 = acc1;
            for (int j = wv + 1; j < 16; ++j)
                if (sh_cq[j] == cq) { s0 += sh_a0[j * 64 + lane]; s1 += sh_a1[j * 64 + lane]; }
            atomicAdd(&Xnew[cq * FEAT + lane], s0);
            atomicAdd(&Xnew[cq * FEAT + 64 + lane], s1);
        }
        // ---- A-count (diagonal keys skipped; d_out pre-zeroed) ----
        int cp = valid ? cluster[myp] : 0;
        bool av = valid && (cp != cq);
        wave_agg_add(av, cp * N + cq, 1.0f, Anew, 1, 0);
    } else {
        // ---- zero [Anew|new_batch], signal, exit (never spins) ----
        float4 z = {0.f, 0.f, 0.f, 0.f};
        float4* az = (float4*)Anew;
        int base = (blk - GATB - 1) * 4096;
        #pragma unroll
        for (int k = 0; k < 4; ++k) {
            int idx = base + k * 1024 + t;
            if (idx < AZ4) az[idx] = z;
        }
        __syncthreads();
        __threadfence();
        if (t == 0) atomicAdd(&ctrl[3], 1);
    }
}

extern "C" void kernel_launch(void* const* d_in, const int* in_sizes, int n_in,
                              void* d_out, int out_size, void* d_ws, size_t ws_size,
                              hipStream_t stream) {
    const float* x  = (const float*)d_in[0];
    const int*   ei = (const int*)d_in[1];
    const float* w  = (const float*)d_in[3];
    const float* bb = (const float*)d_in[4];

    // workspace layout — zero region FIRST: [ctrl(64B) | pcnt | notsing] = 24,640 B
    char* ws = (char*)d_ws;
    size_t off = 0;
    int* ctrl     = (int*)(ws + off);      off += 64;
    int* pcnt     = (int*)(ws + off);      off += (size_t)N * 4;
    int* notsing  = (int*)(ws + off);      off += (size_t)N * 4;
    float* a      = (float*)(ws + off);    off += (size_t)N * 4;
    float* c      = (float*)(ws + off);    off += (size_t)N * 4;
    int* cluster  = (int*)(ws + off);      off += (size_t)N * 4;
    unsigned* ep  = (unsigned*)(ws + off); off += (size_t)NE * 4;
    unsigned long long* ptab = (unsigned long long*)(ws + off); off += (size_t)N * PSTRIDE * 8;

    // output layout (all float32)
    float* Xnew        = (float*)d_out;                 // N*FEAT
    float* Anew        = Xnew + (size_t)N * FEAT;       // N*N
    float* out_cluster = Anew + (size_t)N * N + N;      // after new_batch (zeros)

    k_init<<<DOTB + 1, 256, 0, stream>>>(x, w, a, c, (float4*)ctrl);
    k_edge_pairs<<<NE / 256, 256, 0, stream>>>(ei, a, c, bb, ep, notsing, pcnt, ptab);
    k_pgr2<<<1 + GATB + AZB, 1024, 0, stream>>>(ep, x, pcnt, ptab, notsing,
                                                cluster, out_cluster, Xnew, Anew, ctrl);
}

// Round 12
// 177.418 us; speedup vs baseline: 2.1836x; 2.1836x over previous
//
#include <hip/hip_runtime.h>
#include <math.h>

#define N 3072
#define FEAT 128
#define NE 24576
#define PSTRIDE 64         // per-node pair-slot row stride
#define DOTB 768           // k_init dot blocks (4 nodes each)
#define OZ4 2459136        // f4 count of entire d_out (9,836,544 floats)
#define OZB 2402           // d_out zero blocks (1024 f4 each, bounds-checked)
#define NBLK 256           // mega blocks: 1/CU, guaranteed co-resident
#define RESCAP 4096        // residual-edge LDS capacity

// Wave-aggregated atomic add: one atomicAdd per distinct key per wave.
// All 64 lanes must reach this call (use `valid`, not early-return).
__device__ __forceinline__ void wave_agg_add(bool valid, int key, float val,
                                             float* base, int stride, int off) {
    int lane = threadIdx.x & 63;
    unsigned long long active = __ballot(valid ? 1 : 0);
    while (active) {
        int leader = __ffsll(active) - 1;
        int lkey = __shfl(key, leader);
        bool mine = valid && (key == lkey);
        unsigned long long grp = __ballot(mine ? 1 : 0);
        float v = mine ? val : 0.0f;
        #pragma unroll
        for (int o = 32; o; o >>= 1) v += __shfl_xor(v, o);
        if (lane == leader)
            atomicAdd(&base[(size_t)lkey * stride + off], v);
        active &= ~grp;
    }
}

// Device-scope sense barrier (R7-proven at 256 co-resident blocks).
__device__ __forceinline__ void gsync(int* bar, int* lgen) {
    __syncthreads();
    if (threadIdx.x == 0) {
        __threadfence();
        int g = ++(*lgen);
        if (atomicAdd(&bar[0], 1) == (int)gridDim.x - 1) {
            __hip_atomic_store(&bar[0], 0, __ATOMIC_RELAXED, __HIP_MEMORY_SCOPE_AGENT);
            __threadfence();
            atomicAdd(&bar[1], 1);
        } else {
            while (__hip_atomic_load(&bar[1], __ATOMIC_RELAXED,
                                     __HIP_MEMORY_SCOPE_AGENT) < g)
                __builtin_amdgcn_s_sleep(8);
        }
        __threadfence();
    } else {
        ++(*lgen);
    }
    __syncthreads();
}

// blocks [0,DOTB): a[i]=x[i].w[0:128], c[i]=x[i].w[128:256] (wave per node)
// blocks [DOTB,DOTB+OZB): zero entire d_out
// block DOTB+OZB: zero [bar(64B)|pcnt|notsing] (1540 f4)
__global__ void k_init(const float* __restrict__ x, const float* __restrict__ w,
                       float* __restrict__ a, float* __restrict__ c,
                       float4* __restrict__ zout, float4* __restrict__ zws) {
    int b = blockIdx.x, t = threadIdx.x;
    if (b < DOTB) {
        int node = b * 4 + (t >> 6);
        int lane = t & 63;
        const float* xi = x + node * FEAT;
        float pa = xi[lane] * w[lane] + xi[lane + 64] * w[lane + 64];
        float pc = xi[lane] * w[FEAT + lane] + xi[lane + 64] * w[FEAT + lane + 64];
        for (int off = 32; off; off >>= 1) {
            pa += __shfl_down(pa, off);
            pc += __shfl_down(pc, off);
        }
        if (lane == 0) { a[node] = pa; c[node] = pc; }
    } else if (b < DOTB + OZB) {
        float4 z = {0.f, 0.f, 0.f, 0.f};
        int base = (b - DOTB) * 1024;
        #pragma unroll
        for (int k = 0; k < 4; ++k) {
            int idx = base + k * 256 + t;
            if (idx < OZ4) zout[idx] = z;
        }
    } else {
        float4 z = {0.f, 0.f, 0.f, 0.f};
        #pragma unroll
        for (int k = 0; k < 7; ++k) {
            int idx = k * 256 + t;
            if (idx < 1540) zws[idx] = z;
        }
    }
}

// 256 co-resident blocks:
// phase1: edges (96/block) -> gsync
// phase2: block0 = V-bitmap fixpoint + rank + cluster; blocks 1..192 = gather
// -> gsync ; phase3: strided X-reduce + A-count.
__global__ void __launch_bounds__(1024)
k_mega2(const int* __restrict__ ei, const float* __restrict__ x,
        const float* __restrict__ a, const float* __restrict__ c,
        const float* __restrict__ bb, int* __restrict__ bar,
        int* __restrict__ pcnt, int* __restrict__ notsingle,
        unsigned* __restrict__ ep, unsigned long long* __restrict__ ptab,
        unsigned long long* __restrict__ qmask, float* __restrict__ y,
        int* __restrict__ cluster, float* __restrict__ out_cluster,
        float* __restrict__ Xnew, float* __restrict__ Anew) {
    __shared__ int lab[N];
    __shared__ unsigned Vw[N / 32];
    __shared__ unsigned res[RESCAP];
    __shared__ unsigned short rnodes[N];
    __shared__ int ssum[1024];
    __shared__ unsigned short rk[N];
    __shared__ int sh_p[16 * 64];
    __shared__ int flag, rescnt, rncnt;
    int t = threadIdx.x, blk = blockIdx.x;
    int wv = t >> 6, lane = t & 63;
    int lgen = 0;

    // ---- phase 1: 96 edges per block (NE = 256*96) ----
    if (t < 96) {
        int s = blk * 96 + t;
        int u = ei[s], v = ei[NE + s];
        unsigned wpk = (unsigned)u | ((unsigned)v << 12);
        if (u != v) {
            float b = bb[0];
            float su = a[u] + c[v] + b;    // S[u,v]; A_c[u,v]  (edge u->v)
            float sv = a[v] + c[u] + b;    // S[v,u]; A_c[v,u]  (edge v->u)
            unsigned fu = (su > 0.f) ? 1u : 0u;
            unsigned fv = (sv > 0.f) ? 1u : 0u;
            wpk |= (fu << 24) | (fv << 25);
            if (fu | fv) { notsingle[u] = 1; notsingle[v] = 1; }
            float eu = tanhf(su);
            int sl = atomicAdd(&pcnt[v], 1);
            if (sl < PSTRIDE)
                ptab[(size_t)v * PSTRIDE + sl] =
                    ((unsigned long long)__float_as_uint(eu) << 32) | (unsigned)u;
            float ev2 = tanhf(sv);
            sl = atomicAdd(&pcnt[u], 1);
            if (sl < PSTRIDE)
                ptab[(size_t)u * PSTRIDE + sl] =
                    ((unsigned long long)__float_as_uint(ev2) << 32) | (unsigned)v;
        }
        ep[s] = wpk;
    }
    gsync(bar, &lgen);

    // ---- phase 2 ----
    if (blk == 0) {
        if (t < N / 32) Vw[t] = (t == 0) ? 1u : 0u;
        if (t == 0) { rescnt = 0; rncnt = 0; }
        unsigned act = 0x00FFFFFFu;          // 24 edges per thread, strided
        for (;;) {
            __syncthreads();
            if (t == 0) flag = 0;
            __syncthreads();
            unsigned rem = act;
            while (rem) {
                int j = __ffs(rem) - 1;
                rem &= rem - 1;
                unsigned wpk = ep[t + j * 1024];
                if (!(wpk & 0x3000000u)) { act &= ~(1u << j); continue; }
                int u = wpk & 0xFFF, v = (wpk >> 12) & 0xFFF;
                unsigned pu = (Vw[u >> 5] >> (u & 31)) & 1u;
                unsigned pv = (Vw[v >> 5] >> (v & 31)) & 1u;
                if ((wpk & (1u << 24)) && pv && !pu) {
                    atomicOr(&Vw[u >> 5], 1u << (u & 31)); pu = 1; flag = 1;
                }
                if ((wpk & (1u << 25)) && pu && !pv) {
                    atomicOr(&Vw[v >> 5], 1u << (v & 31)); pv = 1; flag = 1;
                }
                bool done = (pu || !(wpk & (1u << 24))) && (pv || !(wpk & (1u << 25)));
                if (done) act &= ~(1u << j);
            }
            __syncthreads();
            if (!flag) break;
        }
        // compact residue (sources not in V); residue is closed under out-edges
        unsigned rem = act;
        while (rem) {
            int j = __ffs(rem) - 1;
            rem &= rem - 1;
            unsigned wpk = ep[t + j * 1024];
            int u = wpk & 0xFFF, v = (wpk >> 12) & 0xFFF;
            unsigned pu = (Vw[u >> 5] >> (u & 31)) & 1u;
            unsigned pv = (Vw[v >> 5] >> (v & 31)) & 1u;
            if ((wpk & (1u << 24)) && !pu) {
                int pos = atomicAdd(&rescnt, 1);
                if (pos < RESCAP) res[pos] = (unsigned)u | ((unsigned)v << 12);
            }
            if ((wpk & (1u << 25)) && !pv) {
                int pos = atomicAdd(&rescnt, 1);
                if (pos < RESCAP) res[pos] = (unsigned)v | ((unsigned)u << 12);
            }
        }
        for (int i = t; i < N; i += 1024) {
            unsigned inV = (Vw[i >> 5] >> (i & 31)) & 1u;
            lab[i] = inV ? 0 : i;
            if (!inV) {
                int pos = atomicAdd(&rncnt, 1);
                rnodes[pos] = (unsigned short)i;
            }
        }
        __syncthreads();
        int nres = rescnt < RESCAP ? rescnt : RESCAP;
        bool ovf = (rescnt > RESCAP);
        int nrn = rncnt;
        for (;;) {
            __syncthreads();
            if (t == 0) flag = 0;
            __syncthreads();
            if (!ovf) {
                for (int k = t; k < nres; k += 1024) {
                    unsigned w2 = res[k];
                    int p = w2 & 0xFFF, q = (w2 >> 12) & 0xFFF;
                    int lq = lab[q];
                    if (lq < lab[p]) { atomicMin(&lab[p], lq); flag = 1; }
                }
                for (int k = t; k < nrn; k += 1024) {
                    int i = rnodes[k];
                    int m = lab[i];
                    int mm = lab[m];
                    while (mm < m) { m = mm; mm = lab[m]; }
                    if (m < lab[i]) { atomicMin(&lab[i], m); flag = 1; }
                }
            } else {
                for (int j = 0; j < 24; ++j) {
                    unsigned wpk = ep[t + j * 1024];
                    int u = wpk & 0xFFF, v = (wpk >> 12) & 0xFFF;
                    if (wpk & (1u << 24)) {
                        int lv = lab[v];
                        if (lv < lab[u]) { atomicMin(&lab[u], lv); flag = 1; }
                    }
                    if (wpk & (1u << 25)) {
                        int lu = lab[u];
                        if (lu < lab[v]) { atomicMin(&lab[v], lu); flag = 1; }
                    }
                }
                for (int i = t; i < N; i += 1024) {
                    int m = lab[i];
                    if (m == 0) continue;
                    int mm = lab[m];
                    while (mm < m) { m = mm; mm = lab[m]; }
                    if (m < lab[i]) { atomicMin(&lab[i], m); flag = 1; }
                }
            }
            __syncthreads();
            if (!flag) break;
        }
        // rank roots: cumsum(lab[i]==i)-1; cluster[j]=rank[lab[j]]
        int i0 = 3 * t;
        int r0 = (lab[i0] == i0);
        int r1 = (lab[i0 + 1] == i0 + 1);
        int r2 = (lab[i0 + 2] == i0 + 2);
        int s = r0 + r1 + r2;
        ssum[t] = s;
        __syncthreads();
        for (int off = 1; off < 1024; off <<= 1) {
            int val = (t >= off) ? ssum[t - off] : 0;
            __syncthreads();
            ssum[t] += val;
            __syncthreads();
        }
        int run = ssum[t] - s;
        run += r0; rk[i0]     = (unsigned short)(run - 1);
        run += r1; rk[i0 + 1] = (unsigned short)(run - 1);
        run += r2; rk[i0 + 2] = (unsigned short)(run - 1);
        __syncthreads();
        for (int j = t; j < N; j += 1024) {
            int cl = rk[lab[j]];
            cluster[j] = cl;
            out_cluster[j] = (float)cl;
        }
    } else if (blk <= 192) {
        int q = (blk - 1) * 16 + wv;
        int cnt = pcnt[q]; if (cnt > PSTRIDE) cnt = PSTRIDE;
        const unsigned long long* row = ptab + (size_t)q * PSTRIDE;
        int myp = -1 - lane;      // unique negative: never matches a real p
        float mye = 0.f;
        if (lane < cnt) {
            unsigned long long s = row[lane];
            myp = (int)(s & 0xFFFFFFFFu);
            mye = __uint_as_float((unsigned)(s >> 32));
        }
        sh_p[wv * 64 + lane] = myp;
        bool dup = false;
        for (int j = 0; j < lane && !dup; ++j)
            dup = (sh_p[wv * 64 + j] == myp);
        bool valid = (lane < cnt) && !dup;
        unsigned long long m = __ballot(valid ? 1 : 0);
        if (lane == 0) qmask[q] = m;
        float acc0 = 0.f, acc1 = 0.f;
        for (int j = 0; j < cnt; ++j) {
            if (!((m >> j) & 1ull)) continue;
            int p = __shfl(myp, j);
            float e = __shfl(mye, j);
            const float* xp = x + p * FEAT;
            acc0 += e * xp[lane];
            acc1 += e * xp[lane + 64];
        }
        if (!notsingle[q]) {
            const float* xq = x + q * FEAT;
            acc0 += xq[lane];
            acc1 += xq[lane + 64];
        }
        float* yq = y + q * FEAT;
        yq[lane] = acc0;
        yq[lane + 64] = acc1;
    }
    gsync(bar, &lgen);

    // ---- phase 3: gwaves [0,6144): X-reduce; [6144,9216): A-count ----
    for (int gw = blk * 16 + wv; gw < 9216; gw += NBLK * 16) {
        if (gw < 6144) {
            int f = gw & (FEAT - 1);
            int chunk = gw >> 7;
            int q = chunk * 64 + lane;
            wave_agg_add(true, cluster[q], y[q * FEAT + f], Xnew, FEAT, f);
        } else {
            int q = gw - 6144;
            int cnt = pcnt[q]; if (cnt > PSTRIDE) cnt = PSTRIDE;
            unsigned long long m = qmask[q];
            bool valid = (lane < cnt) && ((m >> lane) & 1ull);
            int p = 0;
            if (valid) p = (int)(ptab[(size_t)q * PSTRIDE + lane] & 0xFFFFFFFFu);
            int cq = cluster[q];
            int cp = valid ? cluster[p] : 0;
            valid = valid && (cp != cq);
            wave_agg_add(valid, cp * N + cq, 1.0f, Anew, 1, 0);
        }
    }
}

extern "C" void kernel_launch(void* const* d_in, const int* in_sizes, int n_in,
                              void* d_out, int out_size, void* d_ws, size_t ws_size,
                              hipStream_t stream) {
    const float* x  = (const float*)d_in[0];
    const int*   ei = (const int*)d_in[1];
    const float* w  = (const float*)d_in[3];
    const float* bb = (const float*)d_in[4];

    // workspace layout — zero region FIRST: [bar(64B) | pcnt | notsing] = 24,640 B
    char* ws = (char*)d_ws;
    size_t off = 0;
    int* bar      = (int*)(ws + off);      off += 64;
    int* pcnt     = (int*)(ws + off);      off += (size_t)N * 4;
    int* notsing  = (int*)(ws + off);      off += (size_t)N * 4;
    float* a      = (float*)(ws + off);    off += (size_t)N * 4;
    float* c      = (float*)(ws + off);    off += (size_t)N * 4;
    int* cluster  = (int*)(ws + off);      off += (size_t)N * 4;
    unsigned* ep  = (unsigned*)(ws + off); off += (size_t)NE * 4;
    unsigned long long* qmask = (unsigned long long*)(ws + off); off += (size_t)N * 8;
    float* y      = (float*)(ws + off);    off += (size_t)N * FEAT * 4;
    unsigned long long* ptab = (unsigned long long*)(ws + off); off += (size_t)N * PSTRIDE * 8;

    // output layout (all float32)
    float* Xnew        = (float*)d_out;                 // N*FEAT
    float* Anew        = Xnew + (size_t)N * FEAT;       // N*N
    float* out_cluster = Anew + (size_t)N * N + N;      // after new_batch (zeros)

    k_init<<<DOTB + OZB + 1, 256, 0, stream>>>(x, w, a, c,
                                               (float4*)d_out, (float4*)bar);
    k_mega2<<<NBLK, 1024, 0, stream>>>(ei, x, a, c, bb, bar, pcnt, notsing,
                                       ep, ptab, qmask, y, cluster,
                                       out_cluster, Xnew, Anew);
}